// Round 9
// baseline (126.579 us; speedup 1.0000x reference)
//
#include <hip/hip_runtime.h>
#include <float.h>

// Chamfer L2, B=4, N=M=8192 fp32 -> scalar.
// R9: bf16 MFMA (v_mfma_f32_32x32x16_bf16). fp32 VALU floor (~40us wall) was
// the R5-R8 plateau: CDNA4 v_pk_fma_f32 is half-rate/component (157.3 TF
// vector peak = scalar rate), so only matrix cores go faster.
//
// Distance fully K-packed (K=16 exactly):
//   A[k] = [qh(3), ql(3), qh(3), ql(3), 1, 1, qnh, qnl]
//   B[k] = [ph(3), ph(3), pl(3), pl(3), wh, wl, 1, 1]
//   where qh/ql = bf16 hi/lo split of q (q ~= qh+ql to 2^-17 rel),
//   qnh+qnl ~= -0.5|q|^2, wh+wl ~= -0.5|p|^2.
//   => acc = q.p - 0.5|p|^2 - 0.5|q|^2 = -0.5 d ; d = -2*acc, min d = -2*max acc.
// Epilogue: 1 v_max per acc element in-loop; per-block cross-lane row-reduce
// (shfl_xor over the 32-col lanes) once at the end; unique-producer store to
// part[pchunk][qid] (2 MB ws), then min-over-8 + sum kernel.
//
// C layout (HW-verified m74/m101): col=lane&31, row=(reg&3)+8*(reg>>2)+4*(lane>>5).
// A layout: row m=lane&31, k=(lane>>5)*8+j. B: col n=lane&31, same k split.
// (any k-permutation cancels since A and B are packed with identical coords.)

typedef short sh8   __attribute__((ext_vector_type(8)));
typedef float f32x16 __attribute__((ext_vector_type(16)));

#define BLK   256
#define BATCH 4
#define NPTS  8192
#define PCH   8                      // point chunks
#define PCHUNK (NPTS / PCH)          // 1024 points staged (32 KB LDS)
#define QPB   128                    // queries per block (4 waves x 32)
#define QTILES (NPTS / QPB)          // 64
#define GRID  (2 * BATCH * QTILES * PCH)  // 4096
#define TOTQ  (2 * BATCH * NPTS)          // 65536
#define WS_NEED ((size_t)PCH * TOTQ * sizeof(float))  // 2 MB
#define ONEBF 0x3F80

__device__ __forceinline__ short f2bf(float f) {
    unsigned u = __float_as_uint(f);
    unsigned r = (u + 0x7FFFu + ((u >> 16) & 1u)) >> 16;
    return (short)r;
}
__device__ __forceinline__ float bf2f(short h) {
    return __uint_as_float(((unsigned)(unsigned short)h) << 16);
}

__global__ void zero_out_kernel(float* out) { out[0] = 0.f; }

__global__ __launch_bounds__(BLK) void cd_mfma_kernel(
    const float* __restrict__ p1, const float* __restrict__ p2,
    float* __restrict__ part)
{
    __shared__ uint4 ptsB[PCHUNK * 2];   // per point: 2x uint4 (16 bf16), 32 KB

    int bid    = blockIdx.x;
    int pchunk = bid & (PCH - 1);
    int qt     = (bid >> 3) & (QTILES - 1);
    int batch  = (bid >> 9) & (BATCH - 1);
    int dir    = bid >> 11;

    const float* qbase = (dir == 0 ? p1 : p2) + (size_t)batch * NPTS * 3;
    const float* dbase = (dir == 0 ? p2 : p1) + (size_t)batch * NPTS * 3;

    int tid  = threadIdx.x;
    int wave = tid >> 6;
    int lane = tid & 63;

    // ---- stage 1024 points: 4 consecutive points/thread ----
    {
        int t4 = tid * 4;
        const float* s = dbase + (size_t)(pchunk * PCHUNK + t4) * 3;
        float4 f0 = *(const float4*)(s);
        float4 f1 = *(const float4*)(s + 4);
        float4 f2 = *(const float4*)(s + 8);
        float px[4] = {f0.x, f0.w, f1.z, f2.y};
        float py[4] = {f0.y, f1.x, f1.w, f2.z};
        float pz[4] = {f0.z, f1.y, f2.x, f2.w};
        #pragma unroll
        for (int i = 0; i < 4; ++i) {
            float x = px[i], y = py[i], z = pz[i];
            short hx = f2bf(x), hy = f2bf(y), hz = f2bf(z);
            short lx = f2bf(x - bf2f(hx));
            short ly = f2bf(y - bf2f(hy));
            short lz = f2bf(z - bf2f(hz));
            float w = -0.5f * (x * x + y * y + z * z);
            short wh = f2bf(w);
            short wl = f2bf(w - bf2f(wh));
            unsigned uhx = (unsigned short)hx, uhy = (unsigned short)hy, uhz = (unsigned short)hz;
            unsigned ulx = (unsigned short)lx, uly = (unsigned short)ly, ulz = (unsigned short)lz;
            // half0 shorts: [phx phy phz phx phy phz plx ply]
            ptsB[(t4 + i) * 2 + 0] = make_uint4(
                uhx | (uhy << 16), uhz | (uhx << 16),
                uhy | (uhz << 16), ulx | (uly << 16));
            // half1 shorts: [plz plx ply plz wh wl 1 1]
            ptsB[(t4 + i) * 2 + 1] = make_uint4(
                ulz | (ulx << 16), uly | (ulz << 16),
                (unsigned)(unsigned short)wh | ((unsigned)(unsigned short)wl << 16),
                ((unsigned)ONEBF) | (((unsigned)ONEBF) << 16));
        }
    }

    // ---- A fragment: one query per lane-pair ----
    sh8 afrag;
    {
        int q = qt * QPB + wave * 32 + (lane & 31);
        const float* s = qbase + (size_t)q * 3;
        float x = s[0], y = s[1], z = s[2];
        short hx = f2bf(x), hy = f2bf(y), hz = f2bf(z);
        short lx = f2bf(x - bf2f(hx));
        short ly = f2bf(y - bf2f(hy));
        short lz = f2bf(z - bf2f(hz));
        float w = -0.5f * (x * x + y * y + z * z);
        short nh = f2bf(w);
        short nl = f2bf(w - bf2f(nh));
        int h = lane >> 5;
        // half0: [qhx qhy qhz qlx qly qlz qhx qhy]
        // half1: [qhz qlx qly qlz  1   1  qnh qnl]
        afrag[0] = h ? hz : hx;
        afrag[1] = h ? lx : hy;
        afrag[2] = h ? ly : hz;
        afrag[3] = h ? lz : lx;
        afrag[4] = h ? (short)ONEBF : ly;
        afrag[5] = h ? (short)ONEBF : lz;
        afrag[6] = h ? nh : hx;
        afrag[7] = h ? nl : hy;
    }
    __syncthreads();

    f32x16 zc;
    f32x16 runmax;
    #pragma unroll
    for (int i = 0; i < 16; ++i) { zc[i] = 0.f; runmax[i] = -FLT_MAX; }

    const sh8* bptr = (const sh8*)ptsB;
    int boff = (lane & 31) * 2 + (lane >> 5);   // sh8 index within a tile row

    // ---- 32 tiles of 32 points ----
    #pragma unroll 4
    for (int t = 0; t < PCHUNK / 32; ++t) {
        sh8 bfrag = bptr[t * 64 + boff];
        f32x16 acc = __builtin_amdgcn_mfma_f32_32x32x16_bf16(afrag, bfrag, zc, 0, 0, 0);
        runmax = __builtin_elementwise_max(runmax, acc);
    }

    // ---- row-reduce over the 32 col-lanes (xor net stays within 32-group) ----
    #pragma unroll
    for (int step = 1; step <= 16; step <<= 1) {
        f32x16 o;
        #pragma unroll
        for (int i = 0; i < 16; ++i) o[i] = __shfl_xor(runmax[i], step, 64);
        runmax = __builtin_elementwise_max(runmax, o);
    }

    if ((lane & 31) == 0) {
        int half = lane >> 5;
        int qglob = dir * (BATCH * NPTS) + batch * NPTS + qt * QPB + wave * 32;
        float* prow = part + (size_t)pchunk * TOTQ + qglob;
        #pragma unroll
        for (int reg = 0; reg < 16; ++reg) {
            int r = (reg & 3) + 8 * (reg >> 2) + 4 * half;
            float d = fmaxf(-2.f * runmax[reg], 0.f);
            prow[r] = d;
        }
    }
}

// Stage 2: per query min over PCH chunks, then block-sum -> atomicAdd out.
__global__ __launch_bounds__(BLK) void min_sum_kernel(
    const float* __restrict__ part, float* __restrict__ out, float scale)
{
    int qid = blockIdx.x * BLK + threadIdx.x;
    float v = FLT_MAX;
    #pragma unroll
    for (int m = 0; m < PCH; ++m)
        v = fminf(v, part[(size_t)m * TOTQ + qid]);
    for (int off = 32; off > 0; off >>= 1) v += __shfl_down(v, off, 64);
    __shared__ float wsum[BLK / 64];
    int lane = threadIdx.x & 63, wid = threadIdx.x >> 6;
    if (lane == 0) wsum[wid] = v;
    __syncthreads();
    if (threadIdx.x == 0) {
        float t = 0.f;
        for (int w = 0; w < BLK / 64; ++w) t += wsum[w];
        atomicAdd(out, t * scale);
    }
}

// ---- fallback path (ws too small): fp32 VALU + atomicMin (R7 structure) ----
typedef float v2f __attribute__((ext_vector_type(2)));
typedef float v4f __attribute__((ext_vector_type(4)));
#define FQPT   8
#define FNCH   32
#define FCHUNK (NPTS / FNCH)

__global__ __launch_bounds__(BLK) void init_kernel(unsigned* mins, float* out, int n) {
    int i = blockIdx.x * BLK + threadIdx.x;
    if (i < n) mins[i] = 0x7F7FFFFFu;
    if (i == 0) out[0] = 0.f;
}

__global__ __launch_bounds__(BLK) void cd_chunk_atomic_kernel(
    const float* __restrict__ p1, const float* __restrict__ p2,
    unsigned* __restrict__ mins)
{
    __shared__ v4f pts[FCHUNK];
    int bid    = blockIdx.x;
    int mchunk = bid & (FNCH - 1);
    int qt     = (bid >> 5) & 3;
    int batch  = (bid >> 7) & (BATCH - 1);
    int dir    = bid >> 9;
    const float* qbase = (dir == 0 ? p1 : p2) + (size_t)batch * NPTS * 3;
    const float* dbase = (dir == 0 ? p2 : p1) + (size_t)batch * NPTS * 3;
    int tid = threadIdx.x;
    if (tid < FCHUNK / 4) {
        int t4 = tid * 4;
        const float* s = dbase + (size_t)(mchunk * FCHUNK + t4) * 3;
        float4 f0 = *(const float4*)(s);
        float4 f1 = *(const float4*)(s + 4);
        float4 f2 = *(const float4*)(s + 8);
        float x0 = f0.x, y0 = f0.y, z0 = f0.z;
        float x1 = f0.w, y1 = f1.x, z1 = f1.y;
        float x2 = f1.z, y2 = f1.w, z2 = f2.x;
        float x3 = f2.y, y3 = f2.z, z3 = f2.w;
        float w0 = -0.5f * (x0*x0 + y0*y0 + z0*z0);
        float w1 = -0.5f * (x1*x1 + y1*y1 + z1*z1);
        float w2 = -0.5f * (x2*x2 + y2*y2 + z2*z2);
        float w3 = -0.5f * (x3*x3 + y3*y3 + z3*z3);
        pts[4*tid + 0] = (v4f){x0, x1, y0, y1};
        pts[4*tid + 1] = (v4f){z0, z1, w0, w1};
        pts[4*tid + 2] = (v4f){x2, x3, y2, y3};
        pts[4*tid + 3] = (v4f){z2, z3, w2, w3};
    }
    v2f qx2[FQPT], qy2[FQPT], qz2[FQPT];
    float qn[FQPT];
    #pragma unroll
    for (int k = 0; k < FQPT; ++k) {
        int q = qt * (BLK * FQPT) + k * BLK + tid;
        const float* s = qbase + (size_t)q * 3;
        float qx = s[0], qy = s[1], qz = s[2];
        qx2[k] = (v2f){qx, qx}; qy2[k] = (v2f){qy, qy}; qz2[k] = (v2f){qz, qz};
        qn[k] = qx * qx + qy * qy + qz * qz;
    }
    __syncthreads();
    v2f acc0[FQPT], acc1[FQPT];
    #pragma unroll
    for (int k = 0; k < FQPT; ++k) {
        acc0[k] = (v2f){-FLT_MAX, -FLT_MAX};
        acc1[k] = (v2f){-FLT_MAX, -FLT_MAX};
    }
    #pragma unroll 2
    for (int m = 0; m < FCHUNK / 2; m += 2) {
        v4f u0 = pts[2*m + 0], v0 = pts[2*m + 1];
        v4f u1 = pts[2*m + 2], v1 = pts[2*m + 3];
        v2f X0 = __builtin_shufflevector(u0, u0, 0, 1);
        v2f Y0 = __builtin_shufflevector(u0, u0, 2, 3);
        v2f Z0 = __builtin_shufflevector(v0, v0, 0, 1);
        v2f W0 = __builtin_shufflevector(v0, v0, 2, 3);
        v2f X1 = __builtin_shufflevector(u1, u1, 0, 1);
        v2f Y1 = __builtin_shufflevector(u1, u1, 2, 3);
        v2f Z1 = __builtin_shufflevector(v1, v1, 0, 1);
        v2f W1 = __builtin_shufflevector(v1, v1, 2, 3);
        #pragma unroll
        for (int k = 0; k < FQPT; ++k) {
            v2f s0 = __builtin_elementwise_fma(qz2[k], Z0,
                      __builtin_elementwise_fma(qy2[k], Y0,
                       __builtin_elementwise_fma(qx2[k], X0, W0)));
            acc0[k] = __builtin_elementwise_max(acc0[k], s0);
            v2f s1 = __builtin_elementwise_fma(qz2[k], Z1,
                      __builtin_elementwise_fma(qy2[k], Y1,
                       __builtin_elementwise_fma(qx2[k], X1, W1)));
            acc1[k] = __builtin_elementwise_max(acc1[k], s1);
        }
    }
    unsigned qid = (unsigned)(dir * (BATCH * NPTS) + batch * NPTS + qt * (BLK * FQPT) + tid);
    #pragma unroll
    for (int k = 0; k < FQPT; ++k) {
        float mx = fmaxf(fmaxf(acc0[k].x, acc0[k].y), fmaxf(acc1[k].x, acc1[k].y));
        float d = fmaxf(qn[k] - 2.f * mx, 0.f);
        atomicMin(&mins[qid + k * BLK], __float_as_uint(d));
    }
}

__global__ __launch_bounds__(BLK) void sum_kernel(
    const unsigned* __restrict__ mins, float* __restrict__ out, int n, float scale)
{
    int i = blockIdx.x * BLK + threadIdx.x;
    int stride = gridDim.x * BLK;
    float v = 0.f;
    for (int idx = i; idx < n; idx += stride) v += __uint_as_float(mins[idx]);
    for (int off = 32; off > 0; off >>= 1) v += __shfl_down(v, off, 64);
    __shared__ float wsum[BLK / 64];
    int lane = threadIdx.x & 63, wid = threadIdx.x >> 6;
    if (lane == 0) wsum[wid] = v;
    __syncthreads();
    if (threadIdx.x == 0) {
        float t = 0.f;
        for (int w = 0; w < BLK / 64; ++w) t += wsum[w];
        atomicAdd(out, t * scale);
    }
}

extern "C" void kernel_launch(void* const* d_in, const int* in_sizes, int n_in,
                              void* d_out, int out_size, void* d_ws, size_t ws_size,
                              hipStream_t stream) {
    const float* p1 = (const float*)d_in[0];
    const float* p2 = (const float*)d_in[1];
    float* out = (float*)d_out;

    if (ws_size >= WS_NEED) {
        float* part = (float*)d_ws;
        zero_out_kernel<<<1, 1, 0, stream>>>(out);
        cd_mfma_kernel<<<GRID, BLK, 0, stream>>>(p1, p2, part);
        min_sum_kernel<<<TOTQ / BLK, BLK, 0, stream>>>(part, out,
                                                       1.f / (float)(BATCH * NPTS));
    } else {
        unsigned* mins = (unsigned*)d_ws;
        init_kernel<<<TOTQ / BLK, BLK, 0, stream>>>(mins, out, TOTQ);
        cd_chunk_atomic_kernel<<<1024, BLK, 0, stream>>>(p1, p2, mins);
        sum_kernel<<<64, BLK, 0, stream>>>(mins, out, TOTQ, 1.f / (float)(BATCH * NPTS));
    }
}

// Round 10
// 95.678 us; speedup vs baseline: 1.3230x; 1.3230x over previous
//
#include <hip/hip_runtime.h>
#include <float.h>

// Chamfer L2, B=4, N=M=8192 fp32 -> scalar.
// bf16 MFMA path (v_mfma_f32_32x32x16_bf16), distance fully K-packed (K=16):
//   A[k] = [qh(3), ql(3), qh(3), ql(3), 1, 1, qnh, qnl]
//   B[k] = [ph(3), ph(3), pl(3), pl(3), wh, wl, 1, 1]
//   acc = q.p - 0.5|p|^2 - 0.5|q|^2 = -0.5 d ; min d = -2 max acc.
// R9 verified numerics (absmax 0) but hit 8-way LDS bank conflicts
// (SQ_LDS_BANK_CONFLICT=2.6e7 ~= 42us/CU) from the [point][half] layout,
// and only 32 MFMAs/wave amortized staging (MfmaUtil 9%).
// R10: [half][point] LDS layout (lane-consecutive 16B reads + stores,
// conflict-free) and QA=4 A-fragment reuse (128 MFMAs/wave, 1 ds_read per
// 4 MFMAs). C layout (HW-verified): col=lane&31, row=(reg&3)+8*(reg>>2)+4*(lane>>5).

typedef short sh8    __attribute__((ext_vector_type(8)));
typedef float f32x16 __attribute__((ext_vector_type(16)));

#define BLK   256
#define BATCH 4
#define NPTS  8192
#define PCH   8                      // point chunks
#define PCHUNK (NPTS / PCH)          // 1024 points staged (32 KB LDS)
#define QA    4                      // A fragments per wave
#define QPW   (QA * 32)              // 128 queries per wave
#define QPB   (4 * QPW)              // 512 queries per block
#define QTILES (NPTS / QPB)          // 16
#define GRID  (2 * BATCH * QTILES * PCH)  // 1024
#define TOTQ  (2 * BATCH * NPTS)          // 65536
#define WS_NEED ((size_t)PCH * TOTQ * sizeof(float))  // 2 MB
#define ONEBF 0x3F80

__device__ __forceinline__ short f2bf(float f) {
    unsigned u = __float_as_uint(f);
    unsigned r = (u + 0x7FFFu + ((u >> 16) & 1u)) >> 16;
    return (short)r;
}
__device__ __forceinline__ float bf2f(short h) {
    return __uint_as_float(((unsigned)(unsigned short)h) << 16);
}

__global__ void zero_out_kernel(float* out) { out[0] = 0.f; }

__global__ __launch_bounds__(BLK, 4) void cd_mfma_kernel(
    const float* __restrict__ p1, const float* __restrict__ p2,
    float* __restrict__ part)
{
    __shared__ uint4 ptsB[2 * PCHUNK];   // [half][point], 32 KB

    int bid    = blockIdx.x;
    int pchunk = bid & (PCH - 1);
    int qt     = (bid >> 3) & (QTILES - 1);
    int batch  = (bid >> 7) & (BATCH - 1);
    int dir    = bid >> 9;

    const float* qbase = (dir == 0 ? p1 : p2) + (size_t)batch * NPTS * 3;
    const float* dbase = (dir == 0 ? p2 : p1) + (size_t)batch * NPTS * 3;

    int tid  = threadIdx.x;
    int wave = tid >> 6;
    int lane = tid & 63;
    int col  = lane & 31;
    int half = lane >> 5;

    // ---- stage 1024 points, 1 point/thread x 4 iters (stores stride 16B) ----
    #pragma unroll
    for (int it = 0; it < PCHUNK / BLK; ++it) {
        int p = tid + it * BLK;
        const float* s = dbase + (size_t)(pchunk * PCHUNK + p) * 3;
        float x = s[0], y = s[1], z = s[2];
        short hx = f2bf(x), hy = f2bf(y), hz = f2bf(z);
        short lx = f2bf(x - bf2f(hx));
        short ly = f2bf(y - bf2f(hy));
        short lz = f2bf(z - bf2f(hz));
        float w = -0.5f * (x * x + y * y + z * z);
        short wh = f2bf(w);
        short wl = f2bf(w - bf2f(wh));
        unsigned uhx = (unsigned short)hx, uhy = (unsigned short)hy, uhz = (unsigned short)hz;
        unsigned ulx = (unsigned short)lx, uly = (unsigned short)ly, ulz = (unsigned short)lz;
        // half0 shorts: [phx phy phz phx phy phz plx ply]
        ptsB[p] = make_uint4(uhx | (uhy << 16), uhz | (uhx << 16),
                             uhy | (uhz << 16), ulx | (uly << 16));
        // half1 shorts: [plz plx ply plz wh wl 1 1]
        ptsB[PCHUNK + p] = make_uint4(
            ulz | (ulx << 16), uly | (ulz << 16),
            (unsigned)(unsigned short)wh | ((unsigned)(unsigned short)wl << 16),
            ((unsigned)ONEBF) | (((unsigned)ONEBF) << 16));
    }

    // ---- A fragments: QA query groups of 32 per wave ----
    sh8 afrag[QA];
    #pragma unroll
    for (int qa = 0; qa < QA; ++qa) {
        int q = qt * QPB + wave * QPW + qa * 32 + col;
        const float* s = qbase + (size_t)q * 3;
        float x = s[0], y = s[1], z = s[2];
        short hx = f2bf(x), hy = f2bf(y), hz = f2bf(z);
        short lx = f2bf(x - bf2f(hx));
        short ly = f2bf(y - bf2f(hy));
        short lz = f2bf(z - bf2f(hz));
        float w = -0.5f * (x * x + y * y + z * z);
        short nh = f2bf(w);
        short nl = f2bf(w - bf2f(nh));
        // half0: [qhx qhy qhz qlx qly qlz qhx qhy]
        // half1: [qhz qlx qly qlz  1   1  qnh qnl]
        afrag[qa][0] = half ? hz : hx;
        afrag[qa][1] = half ? lx : hy;
        afrag[qa][2] = half ? ly : hz;
        afrag[qa][3] = half ? lz : lx;
        afrag[qa][4] = half ? (short)ONEBF : ly;
        afrag[qa][5] = half ? (short)ONEBF : lz;
        afrag[qa][6] = half ? nh : hx;
        afrag[qa][7] = half ? nl : hy;
    }
    __syncthreads();

    f32x16 zc;
    f32x16 runmax[QA];
    #pragma unroll
    for (int i = 0; i < 16; ++i) zc[i] = 0.f;
    #pragma unroll
    for (int qa = 0; qa < QA; ++qa)
        #pragma unroll
        for (int i = 0; i < 16; ++i) runmax[qa][i] = -FLT_MAX;

    const uint4* bbase = ptsB + half * PCHUNK + col;

    // ---- 32 tiles of 32 points; each B tile feeds QA MFMAs ----
    #pragma unroll 2
    for (int t = 0; t < PCHUNK / 32; ++t) {
        sh8 bfrag = *(const sh8*)(bbase + t * 32);
        #pragma unroll
        for (int qa = 0; qa < QA; ++qa) {
            f32x16 acc = __builtin_amdgcn_mfma_f32_32x32x16_bf16(
                afrag[qa], bfrag, zc, 0, 0, 0);
            runmax[qa] = __builtin_elementwise_max(runmax[qa], acc);
        }
    }

    // ---- row-reduce over 32 col-lanes, then store 32 rows per qa ----
    int qglob0 = dir * (BATCH * NPTS) + batch * NPTS + qt * QPB + wave * QPW;
    float* prow = part + (size_t)pchunk * TOTQ + qglob0;
    #pragma unroll
    for (int qa = 0; qa < QA; ++qa) {
        f32x16 rm = runmax[qa];
        #pragma unroll
        for (int step = 1; step <= 16; step <<= 1) {
            f32x16 o;
            #pragma unroll
            for (int i = 0; i < 16; ++i) o[i] = __shfl_xor(rm[i], step, 64);
            rm = __builtin_elementwise_max(rm, o);
        }
        if (col == 0) {
            #pragma unroll
            for (int reg = 0; reg < 16; ++reg) {
                int r = (reg & 3) + 8 * (reg >> 2) + 4 * half;
                prow[qa * 32 + r] = fmaxf(-2.f * rm[reg], 0.f);
            }
        }
    }
}

// Stage 2: per query min over PCH chunks, then block-sum -> atomicAdd out.
__global__ __launch_bounds__(BLK) void min_sum_kernel(
    const float* __restrict__ part, float* __restrict__ out, float scale)
{
    int qid = blockIdx.x * BLK + threadIdx.x;
    float v = FLT_MAX;
    #pragma unroll
    for (int m = 0; m < PCH; ++m)
        v = fminf(v, part[(size_t)m * TOTQ + qid]);
    for (int off = 32; off > 0; off >>= 1) v += __shfl_down(v, off, 64);
    __shared__ float wsum[BLK / 64];
    int lane = threadIdx.x & 63, wid = threadIdx.x >> 6;
    if (lane == 0) wsum[wid] = v;
    __syncthreads();
    if (threadIdx.x == 0) {
        float t = 0.f;
        for (int w = 0; w < BLK / 64; ++w) t += wsum[w];
        atomicAdd(out, t * scale);
    }
}

// ---- fallback path (ws too small): fp32 VALU + atomicMin ----
typedef float v2f __attribute__((ext_vector_type(2)));
typedef float v4f __attribute__((ext_vector_type(4)));
#define FQPT   8
#define FNCH   32
#define FCHUNK (NPTS / FNCH)

__global__ __launch_bounds__(BLK) void init_kernel(unsigned* mins, float* out, int n) {
    int i = blockIdx.x * BLK + threadIdx.x;
    if (i < n) mins[i] = 0x7F7FFFFFu;
    if (i == 0) out[0] = 0.f;
}

__global__ __launch_bounds__(BLK) void cd_chunk_atomic_kernel(
    const float* __restrict__ p1, const float* __restrict__ p2,
    unsigned* __restrict__ mins)
{
    __shared__ v4f pts[FCHUNK];
    int bid    = blockIdx.x;
    int mchunk = bid & (FNCH - 1);
    int qt     = (bid >> 5) & 3;
    int batch  = (bid >> 7) & (BATCH - 1);
    int dir    = bid >> 9;
    const float* qbase = (dir == 0 ? p1 : p2) + (size_t)batch * NPTS * 3;
    const float* dbase = (dir == 0 ? p2 : p1) + (size_t)batch * NPTS * 3;
    int tid = threadIdx.x;
    if (tid < FCHUNK / 4) {
        int t4 = tid * 4;
        const float* s = dbase + (size_t)(mchunk * FCHUNK + t4) * 3;
        float4 f0 = *(const float4*)(s);
        float4 f1 = *(const float4*)(s + 4);
        float4 f2 = *(const float4*)(s + 8);
        float x0 = f0.x, y0 = f0.y, z0 = f0.z;
        float x1 = f0.w, y1 = f1.x, z1 = f1.y;
        float x2 = f1.z, y2 = f1.w, z2 = f2.x;
        float x3 = f2.y, y3 = f2.z, z3 = f2.w;
        float w0 = -0.5f * (x0*x0 + y0*y0 + z0*z0);
        float w1 = -0.5f * (x1*x1 + y1*y1 + z1*z1);
        float w2 = -0.5f * (x2*x2 + y2*y2 + z2*z2);
        float w3 = -0.5f * (x3*x3 + y3*y3 + z3*z3);
        pts[4*tid + 0] = (v4f){x0, x1, y0, y1};
        pts[4*tid + 1] = (v4f){z0, z1, w0, w1};
        pts[4*tid + 2] = (v4f){x2, x3, y2, y3};
        pts[4*tid + 3] = (v4f){z2, z3, w2, w3};
    }
    v2f qx2[FQPT], qy2[FQPT], qz2[FQPT];
    float qn[FQPT];
    #pragma unroll
    for (int k = 0; k < FQPT; ++k) {
        int q = qt * (BLK * FQPT) + k * BLK + tid;
        const float* s = qbase + (size_t)q * 3;
        float qx = s[0], qy = s[1], qz = s[2];
        qx2[k] = (v2f){qx, qx}; qy2[k] = (v2f){qy, qy}; qz2[k] = (v2f){qz, qz};
        qn[k] = qx * qx + qy * qy + qz * qz;
    }
    __syncthreads();
    v2f acc0[FQPT], acc1[FQPT];
    #pragma unroll
    for (int k = 0; k < FQPT; ++k) {
        acc0[k] = (v2f){-FLT_MAX, -FLT_MAX};
        acc1[k] = (v2f){-FLT_MAX, -FLT_MAX};
    }
    #pragma unroll 2
    for (int m = 0; m < FCHUNK / 2; m += 2) {
        v4f u0 = pts[2*m + 0], v0 = pts[2*m + 1];
        v4f u1 = pts[2*m + 2], v1 = pts[2*m + 3];
        v2f X0 = __builtin_shufflevector(u0, u0, 0, 1);
        v2f Y0 = __builtin_shufflevector(u0, u0, 2, 3);
        v2f Z0 = __builtin_shufflevector(v0, v0, 0, 1);
        v2f W0 = __builtin_shufflevector(v0, v0, 2, 3);
        v2f X1 = __builtin_shufflevector(u1, u1, 0, 1);
        v2f Y1 = __builtin_shufflevector(u1, u1, 2, 3);
        v2f Z1 = __builtin_shufflevector(v1, v1, 0, 1);
        v2f W1 = __builtin_shufflevector(v1, v1, 2, 3);
        #pragma unroll
        for (int k = 0; k < FQPT; ++k) {
            v2f s0 = __builtin_elementwise_fma(qz2[k], Z0,
                      __builtin_elementwise_fma(qy2[k], Y0,
                       __builtin_elementwise_fma(qx2[k], X0, W0)));
            acc0[k] = __builtin_elementwise_max(acc0[k], s0);
            v2f s1 = __builtin_elementwise_fma(qz2[k], Z1,
                      __builtin_elementwise_fma(qy2[k], Y1,
                       __builtin_elementwise_fma(qx2[k], X1, W1)));
            acc1[k] = __builtin_elementwise_max(acc1[k], s1);
        }
    }
    unsigned qid = (unsigned)(dir * (BATCH * NPTS) + batch * NPTS + qt * (BLK * FQPT) + tid);
    #pragma unroll
    for (int k = 0; k < FQPT; ++k) {
        float mx = fmaxf(fmaxf(acc0[k].x, acc0[k].y), fmaxf(acc1[k].x, acc1[k].y));
        float d = fmaxf(qn[k] - 2.f * mx, 0.f);
        atomicMin(&mins[qid + k * BLK], __float_as_uint(d));
    }
}

__global__ __launch_bounds__(BLK) void sum_kernel(
    const unsigned* __restrict__ mins, float* __restrict__ out, int n, float scale)
{
    int i = blockIdx.x * BLK + threadIdx.x;
    int stride = gridDim.x * BLK;
    float v = 0.f;
    for (int idx = i; idx < n; idx += stride) v += __uint_as_float(mins[idx]);
    for (int off = 32; off > 0; off >>= 1) v += __shfl_down(v, off, 64);
    __shared__ float wsum[BLK / 64];
    int lane = threadIdx.x & 63, wid = threadIdx.x >> 6;
    if (lane == 0) wsum[wid] = v;
    __syncthreads();
    if (threadIdx.x == 0) {
        float t = 0.f;
        for (int w = 0; w < BLK / 64; ++w) t += wsum[w];
        atomicAdd(out, t * scale);
    }
}

extern "C" void kernel_launch(void* const* d_in, const int* in_sizes, int n_in,
                              void* d_out, int out_size, void* d_ws, size_t ws_size,
                              hipStream_t stream) {
    const float* p1 = (const float*)d_in[0];
    const float* p2 = (const float*)d_in[1];
    float* out = (float*)d_out;

    if (ws_size >= WS_NEED) {
        float* part = (float*)d_ws;
        zero_out_kernel<<<1, 1, 0, stream>>>(out);
        cd_mfma_kernel<<<GRID, BLK, 0, stream>>>(p1, p2, part);
        min_sum_kernel<<<TOTQ / BLK, BLK, 0, stream>>>(part, out,
                                                       1.f / (float)(BATCH * NPTS));
    } else {
        unsigned* mins = (unsigned*)d_ws;
        init_kernel<<<TOTQ / BLK, BLK, 0, stream>>>(mins, out, TOTQ);
        cd_chunk_atomic_kernel<<<1024, BLK, 0, stream>>>(p1, p2, mins);
        sum_kernel<<<64, BLK, 0, stream>>>(mins, out, TOTQ, 1.f / (float)(BATCH * NPTS));
    }
}